// Round 1
// baseline (694.156 us; speedup 1.0000x reference)
//
#include <hip/hip_runtime.h>
#include <hip/hip_bf16.h>

__device__ __forceinline__ float4 ld4(const float* p){ return *reinterpret_cast<const float4*>(p); }

// ---------------- CSR build ----------------
__global__ __launch_bounds__(256) void k_hist(const int* __restrict__ ei, int* __restrict__ cnt, int E_, int Et){
  int e = blockIdx.x*blockDim.x + threadIdx.x;
  if (e < Et){ int d = (e < E_) ? ei[E_ + e] : (e - E_); atomicAdd(&cnt[d], 1); }
}

__global__ __launch_bounds__(1024) void k_scan(const int* __restrict__ cnt, int* __restrict__ off,
                                               int* __restrict__ cursor, int N_){
  __shared__ int partial[1024];
  int t = threadIdx.x;
  int CH = (N_ + 1023) >> 10;
  int lo = t*CH, hi = min(lo+CH, N_);
  int s = 0;
  for (int i=lo;i<hi;i++) s += cnt[i];
  partial[t] = s; __syncthreads();
  for (int d=1; d<1024; d<<=1){
    int v = (t>=d) ? partial[t-d] : 0;
    __syncthreads();
    partial[t] += v;
    __syncthreads();
  }
  int run = partial[t] - s;
  for (int i=lo;i<hi;i++){ off[i]=run; cursor[i]=run; run += cnt[i]; }
  if (t==1023) off[N_] = partial[1023];
}

__global__ __launch_bounds__(256) void k_scatter(const int* __restrict__ ei, int* __restrict__ cursor,
                                                 int* __restrict__ csr_src, int E_, int Et){
  int e = blockIdx.x*blockDim.x + threadIdx.x;
  if (e < Et){
    int d, s;
    if (e < E_){ s = ei[e]; d = ei[E_+e]; } else { s = e-E_; d = e-E_; }
    int pos = atomicAdd(&cursor[d], 1);
    csr_src[pos] = s;
  }
}

// ---------------- fp32 GEMM  [M,128] @ [128,128] ----------------
// EPI=0: C[m][0:128] = A@B ;  EPI=1: outsc[m*3+sc_off] = sum_c tanh((A@B)[m][c]) * aatt[c]
template<int EPI>
__global__ __launch_bounds__(256) void k_gemm128(
    const float* __restrict__ A, const float* __restrict__ B, float* __restrict__ C,
    int M, const float* __restrict__ aatt, float* __restrict__ outsc, int sc_off)
{
  __shared__ float As[32][132];   // As[k][m] = A[r0+m][k0+k]  (stride 132 -> 16B aligned rows)
  __shared__ float Bs[32][128];   // Bs[k][n] = B[k0+k][n]
  int t  = threadIdx.x;
  int tx = t & 15, ty = t >> 4;
  int r0 = blockIdx.x * 128;
  float acc[8][8];
  #pragma unroll
  for (int i=0;i<8;i++)
    #pragma unroll
    for (int j=0;j<8;j++) acc[i][j]=0.f;

  for (int k0=0;k0<128;k0+=32){
    #pragma unroll
    for (int p=0;p<4;p++){
      int i = t + p*256; int row=i>>3, q=i&7;
      float4 v = make_float4(0.f,0.f,0.f,0.f);
      int gr = r0+row;
      if (gr < M) v = ld4(&A[(size_t)gr*128 + k0 + q*4]);
      As[q*4+0][row]=v.x; As[q*4+1][row]=v.y; As[q*4+2][row]=v.z; As[q*4+3][row]=v.w;
    }
    #pragma unroll
    for (int p=0;p<4;p++){
      int i = t + p*256; int kk=i>>5, n4=i&31;
      *reinterpret_cast<float4*>(&Bs[kk][n4*4]) = ld4(&B[(size_t)(k0+kk)*128 + n4*4]);
    }
    __syncthreads();
    #pragma unroll
    for (int kk=0;kk<32;kk++){
      float4 a0 = *reinterpret_cast<float4*>(&As[kk][ty*8]);
      float4 a1 = *reinterpret_cast<float4*>(&As[kk][ty*8+4]);
      float4 b0 = *reinterpret_cast<float4*>(&Bs[kk][tx*8]);
      float4 b1 = *reinterpret_cast<float4*>(&Bs[kk][tx*8+4]);
      float av[8]={a0.x,a0.y,a0.z,a0.w,a1.x,a1.y,a1.z,a1.w};
      float bv[8]={b0.x,b0.y,b0.z,b0.w,b1.x,b1.y,b1.z,b1.w};
      #pragma unroll
      for (int i=0;i<8;i++)
        #pragma unroll
        for (int j=0;j<8;j++)
          acc[i][j] = fmaf(av[i], bv[j], acc[i][j]);
    }
    __syncthreads();
  }

  if (EPI == 0){
    #pragma unroll
    for (int i=0;i<8;i++){
      int gr = r0 + ty*8 + i;
      if (gr < M){
        float4 v0 = make_float4(acc[i][0],acc[i][1],acc[i][2],acc[i][3]);
        float4 v1 = make_float4(acc[i][4],acc[i][5],acc[i][6],acc[i][7]);
        *reinterpret_cast<float4*>(&C[(size_t)gr*128 + tx*8])     = v0;
        *reinterpret_cast<float4*>(&C[(size_t)gr*128 + tx*8 + 4]) = v1;
      }
    }
  } else {
    float4 t0 = ld4(&aatt[tx*8]);
    float4 t1 = ld4(&aatt[tx*8+4]);
    float av8[8]={t0.x,t0.y,t0.z,t0.w,t1.x,t1.y,t1.z,t1.w};
    float part[8];
    #pragma unroll
    for (int i=0;i<8;i++){
      float s = 0.f;
      #pragma unroll
      for (int j=0;j<8;j++) s += tanhf(acc[i][j]) * av8[j];
      part[i]=s;
    }
    float* red = &As[0][0];
    __syncthreads();
    #pragma unroll
    for (int i=0;i<8;i++) red[(ty*8+i)*16 + tx] = part[i];
    __syncthreads();
    if (t < 128){
      float s=0.f;
      #pragma unroll
      for (int x=0;x<16;x++) s += red[t*16+x];
      int gr = r0 + t;
      if (gr < M) outsc[(size_t)gr*3 + sc_off] = s;
    }
  }
}

// ---------------- per-(node,head) attention dots ----------------
__global__ __launch_bounds__(256) void k_sdot(const float* __restrict__ htmp,
    const float* __restrict__ a_s, const float* __restrict__ a_d,
    float* __restrict__ s_src, float* __restrict__ s_dst, int N_)
{
  int tid = blockIdx.x*blockDim.x + threadIdx.x;
  if (tid >= N_*8) return;
  int h = tid & 7;
  const float* hp = htmp + (size_t)(tid>>3)*128 + h*16;
  const float* ap = a_s + h*16;
  const float* dp = a_d + h*16;
  float ss=0.f, dd=0.f;
  #pragma unroll
  for (int q=0;q<4;q++){
    float4 hv = ld4(hp + q*4);
    float4 av = ld4(ap + q*4);
    float4 dv = ld4(dp + q*4);
    ss += hv.x*av.x + hv.y*av.y + hv.z*av.z + hv.w*av.w;
    dd += hv.x*dv.x + hv.y*dv.y + hv.z*dv.z + hv.w*dv.w;
  }
  s_src[tid]=ss; s_dst[tid]=dd;
}

// ---------------- wave-per-node softmax-aggregate ----------------
__global__ __launch_bounds__(256) void k_aggregate(
    const int* __restrict__ off, const int* __restrict__ csr_src,
    const float* __restrict__ htmp, const float* __restrict__ s_src,
    const float* __restrict__ s_dst, const float* __restrict__ bias,
    float* __restrict__ hout, int N_)
{
  __shared__ float esc[4][512];
  __shared__ int   ssrc[4][64];
  int w = threadIdx.x >> 6;
  int lane = threadIdx.x & 63;
  int n = blockIdx.x*4 + w;
  if (n >= N_) return;
  int base = off[n];
  int deg  = off[n+1] - base;
  int myh = lane >> 3;
  float4 sd0 = ld4(&s_dst[(size_t)n*8]);
  float4 sd1 = ld4(&s_dst[(size_t)n*8+4]);
  float sdv[8] = {sd0.x,sd0.y,sd0.z,sd0.w,sd1.x,sd1.y,sd1.z,sd1.w};
  float run_m[8];
  #pragma unroll
  for (int h=0;h<8;h++) run_m[h] = -1e30f;
  float acc0=0.f, acc1=0.f, dsum=0.f;

  for (int cb=0; cb<deg; cb+=64){
    int cdeg = min(64, deg-cb);
    float sc[8];
    int srcj = 0;
    if (lane < cdeg){
      srcj = csr_src[base+cb+lane];
      float4 a0 = ld4(&s_src[(size_t)srcj*8]);
      float4 a1 = ld4(&s_src[(size_t)srcj*8+4]);
      float sv[8]={a0.x,a0.y,a0.z,a0.w,a1.x,a1.y,a1.z,a1.w};
      #pragma unroll
      for (int h=0;h<8;h++){
        float v = sv[h]+sdv[h];
        sc[h] = v>0.f ? v : 0.2f*v;
      }
    } else {
      #pragma unroll
      for (int h=0;h<8;h++) sc[h] = -1e30f;
    }
    // butterfly max per head across the wave
    float cm[8];
    #pragma unroll
    for (int h=0;h<8;h++) cm[h]=sc[h];
    #pragma unroll
    for (int s=1;s<64;s<<=1){
      #pragma unroll
      for (int h=0;h<8;h++) cm[h] = fmaxf(cm[h], __shfl_xor(cm[h], s));
    }
    // online-softmax rescale
    float nm[8];
    #pragma unroll
    for (int h=0;h<8;h++) nm[h] = fmaxf(run_m[h], cm[h]);
    float scale = __expf(run_m[myh] - nm[myh]);
    acc0*=scale; acc1*=scale; dsum*=scale;
    #pragma unroll
    for (int h=0;h<8;h++) run_m[h]=nm[h];

    float eev[8];
    if (lane<cdeg){
      #pragma unroll
      for (int h=0;h<8;h++) eev[h] = __expf(sc[h]-nm[h]);
    } else {
      #pragma unroll
      for (int h=0;h<8;h++) eev[h]=0.f;
    }
    *reinterpret_cast<float4*>(&esc[w][lane*8])   = make_float4(eev[0],eev[1],eev[2],eev[3]);
    *reinterpret_cast<float4*>(&esc[w][lane*8+4]) = make_float4(eev[4],eev[5],eev[6],eev[7]);
    ssrc[w][lane] = srcj;
    asm volatile("s_waitcnt lgkmcnt(0)" ::: "memory");
    __builtin_amdgcn_sched_barrier(0);

    for (int j=0;j<cdeg;j++){
      float ee = esc[w][j*8 + myh];
      int s = ssrc[w][j];
      float2 hv = *reinterpret_cast<const float2*>(&htmp[(size_t)s*128 + 2*lane]);
      acc0 = fmaf(ee, hv.x, acc0);
      acc1 = fmaf(ee, hv.y, acc1);
      dsum += ee;
    }
  }
  float inv = 1.f/(dsum + 1e-16f);
  float o0 = acc0*inv + bias[2*lane];
  float o1 = acc1*inv + bias[2*lane+1];
  o0 = o0>0.f ? o0 : (__expf(o0)-1.f);
  o1 = o1>0.f ? o1 : (__expf(o1)-1.f);
  *reinterpret_cast<float2*>(&hout[(size_t)n*128 + 2*lane]) = make_float2(o0,o1);
}

// ---------------- layer-softmax + output head ----------------
__global__ __launch_bounds__(256) void k_final(
  const float* __restrict__ h0, const float* __restrict__ h1, const float* __restrict__ h2,
  const float* __restrict__ scoresL, const float* __restrict__ Wout, const float* __restrict__ bout,
  float* __restrict__ out, int N_)
{
  __shared__ float hfs[4][128];
  int w = threadIdx.x>>6, lane = threadIdx.x&63;
  int n = blockIdx.x*4 + w;
  if (n>=N_) return;
  float s0 = scoresL[(size_t)n*3+0], s1 = scoresL[(size_t)n*3+1], s2 = scoresL[(size_t)n*3+2];
  float m = fmaxf(s0, fmaxf(s1,s2));
  float e0=__expf(s0-m), e1=__expf(s1-m), e2=__expf(s2-m);
  float inv = 1.f/(e0+e1+e2);
  float l0=e0*inv, l1=e1*inv, l2=e2*inv;
  float2 a = *reinterpret_cast<const float2*>(&h0[(size_t)n*128+2*lane]);
  float2 b = *reinterpret_cast<const float2*>(&h1[(size_t)n*128+2*lane]);
  float2 c = *reinterpret_cast<const float2*>(&h2[(size_t)n*128+2*lane]);
  hfs[w][2*lane]   = l0*a.x + l1*b.x + l2*c.x;
  hfs[w][2*lane+1] = l0*a.y + l1*b.y + l2*c.y;
  asm volatile("s_waitcnt lgkmcnt(0)" ::: "memory");
  __builtin_amdgcn_sched_barrier(0);
  if (lane < 40){
    float accv = bout[lane];
    #pragma unroll 8
    for (int k=0;k<128;k++)
      accv = fmaf(hfs[w][k], Wout[k*40+lane], accv);
    out[(size_t)n*40 + lane] = accv;
  }
}

extern "C" void kernel_launch(void* const* d_in, const int* in_sizes, int n_in,
                              void* d_out, int out_size, void* d_ws, size_t ws_size,
                              hipStream_t stream)
{
  const float* x    = (const float*)d_in[0];
  const int*   ei   = (const int*)d_in[1];
  const float* W0   = (const float*)d_in[2];
  const float* as0  = (const float*)d_in[3];
  const float* ad0  = (const float*)d_in[4];
  const float* b0   = (const float*)d_in[5];
  const float* W12  = (const float*)d_in[6];
  const float* as12 = (const float*)d_in[7];
  const float* ad12 = (const float*)d_in[8];
  const float* b12  = (const float*)d_in[9];
  const float* Watt = (const float*)d_in[10];
  const float* aatt = (const float*)d_in[11];
  const float* Wout = (const float*)d_in[12];
  const float* bout = (const float*)d_in[13];
  const int N_ = in_sizes[0] / 128;
  const int E_ = in_sizes[1] / 2;
  const int Et = E_ + N_;

  char* p = (char*)d_ws;
  auto carve = [&](size_t bytes)->char*{ char* r = p; p += (bytes + 255) & ~(size_t)255; return r; };
  float* htmp    = (float*)carve((size_t)N_*128*4);
  float* h0      = (float*)carve((size_t)N_*128*4);
  float* h1      = (float*)carve((size_t)N_*128*4);
  float* h2      = (float*)carve((size_t)N_*128*4);
  float* ssrc_s  = (float*)carve((size_t)N_*8*4);
  float* sdst_s  = (float*)carve((size_t)N_*8*4);
  float* scoresL = (float*)carve((size_t)N_*3*4);
  int* cnt       = (int*)carve((size_t)N_*4);
  int* offv      = (int*)carve((size_t)(N_+1)*4);
  int* cursor    = (int*)carve((size_t)N_*4);
  int* csr       = (int*)carve((size_t)Et*4);

  hipMemsetAsync(cnt, 0, (size_t)N_*4, stream);
  int gE = (Et + 255)/256;
  k_hist<<<gE,256,0,stream>>>(ei, cnt, E_, Et);
  k_scan<<<1,1024,0,stream>>>(cnt, offv, cursor, N_);
  k_scatter<<<gE,256,0,stream>>>(ei, cursor, csr, E_, Et);

  int gM  = (N_+127)/128;
  int gS  = (N_*8+255)/256;
  int gN4 = (N_+3)/4;
  const float* hin = x;
  float* hl[3] = {h0,h1,h2};
  for (int l=0;l<3;l++){
    const float* W  = (l==0)? W0  : W12  + (size_t)(l-1)*128*128;
    const float* as_= (l==0)? as0 : as12 + (size_t)(l-1)*128;
    const float* ad_= (l==0)? ad0 : ad12 + (size_t)(l-1)*128;
    const float* bb = (l==0)? b0  : b12  + (size_t)(l-1)*128;
    k_gemm128<0><<<gM,256,0,stream>>>(hin, W, htmp, N_, nullptr, nullptr, 0);
    k_sdot<<<gS,256,0,stream>>>(htmp, as_, ad_, ssrc_s, sdst_s, N_);
    k_aggregate<<<gN4,256,0,stream>>>(offv, csr, htmp, ssrc_s, sdst_s, bb, hl[l], N_);
    hin = hl[l];
  }
  for (int l=0;l<3;l++)
    k_gemm128<1><<<gM,256,0,stream>>>(hl[l], Watt, nullptr, N_, aatt, scoresL, l);
  k_final<<<gN4,256,0,stream>>>(h0,h1,h2, scoresL, Wout, bout, (float*)d_out, N_);
}

// Round 2
// 400.614 us; speedup vs baseline: 1.7327x; 1.7327x over previous
//
#include <hip/hip_runtime.h>
#include <hip/hip_bf16.h>

typedef float f32x4 __attribute__((ext_vector_type(4)));
typedef short bf16x8 __attribute__((ext_vector_type(8)));

__device__ __forceinline__ float4 ld4(const float* p){ return *reinterpret_cast<const float4*>(p); }
__device__ __forceinline__ unsigned short f2bf(float f){
  unsigned int u = __float_as_uint(f);
  u = (u + 0x7fffu + ((u>>16)&1u)) >> 16;
  return (unsigned short)u;
}
__device__ __forceinline__ float bflo(unsigned int u){ return __uint_as_float(u<<16); }
__device__ __forceinline__ float bfhi(unsigned int u){ return __uint_as_float(u & 0xffff0000u); }
__device__ __forceinline__ float ftanh(float x){
  float e = __expf(2.f*x);
  return fmaf(-2.f, __builtin_amdgcn_rcpf(e+1.f), 1.f);
}

// ---------------- CSR build ----------------
__global__ __launch_bounds__(256) void k_hist(const int* __restrict__ ei, int* __restrict__ cnt, int E_, int Et){
  int e = blockIdx.x*blockDim.x + threadIdx.x;
  if (e < Et){ int d = (e < E_) ? ei[E_ + e] : (e - E_); atomicAdd(&cnt[d], 1); }
}

__global__ __launch_bounds__(256) void k_scan1(const int* __restrict__ cnt, int* __restrict__ blk, int N_){
  int t = threadIdx.x, b = blockIdx.x;
  int i0 = b*1024 + t*4;
  int s = 0;
  if (i0+3 < N_){ int4 v = *reinterpret_cast<const int4*>(&cnt[i0]); s = v.x+v.y+v.z+v.w; }
  else { for (int j=0;j<4;j++) if (i0+j<N_) s += cnt[i0+j]; }
  #pragma unroll
  for (int d=1; d<64; d<<=1) s += __shfl_xor(s, d);
  __shared__ int ws[4];
  if ((t&63)==0) ws[t>>6] = s;
  __syncthreads();
  if (t==0) blk[b] = ws[0]+ws[1]+ws[2]+ws[3];
}

__global__ __launch_bounds__(64) void k_scan2(const int* __restrict__ blk, int* __restrict__ blkoff,
                                              int* __restrict__ off, int N_, int nblk){
  int l = threadIdx.x;
  int v = (l<nblk)? blk[l] : 0;
  int incl = v;
  #pragma unroll
  for (int d=1; d<64; d<<=1){ int u = __shfl_up(incl, d); if (l>=d) incl += u; }
  if (l<nblk) blkoff[l] = incl - v;
  if (l==63) off[N_] = incl;
}

__global__ __launch_bounds__(256) void k_scan3(const int* __restrict__ cnt, const int* __restrict__ blkoff,
                                               int* __restrict__ off, int* __restrict__ cursor, int N_){
  int t = threadIdx.x, b = blockIdx.x;
  int i0 = b*1024 + t*4;
  int c0=0,c1=0,c2=0,c3=0;
  if (i0+3 < N_){ int4 v = *reinterpret_cast<const int4*>(&cnt[i0]); c0=v.x;c1=v.y;c2=v.z;c3=v.w; }
  else { if(i0<N_)c0=cnt[i0]; if(i0+1<N_)c1=cnt[i0+1]; if(i0+2<N_)c2=cnt[i0+2]; if(i0+3<N_)c3=cnt[i0+3]; }
  int s = c0+c1+c2+c3;
  int incl = s;
  int lane = t&63, w = t>>6;
  #pragma unroll
  for (int d=1; d<64; d<<=1){ int u = __shfl_up(incl, d); if (lane>=d) incl += u; }
  __shared__ int ws[4];
  if (lane==63) ws[w] = incl;
  __syncthreads();
  int wpre = 0;
  #pragma unroll
  for (int k=0;k<4;k++) if (k<w) wpre += ws[k];
  int run = blkoff[b] + wpre + incl - s;
  if (i0  <N_){ off[i0]=run; cursor[i0]=run; }   run += c0;
  if (i0+1<N_){ off[i0+1]=run; cursor[i0+1]=run; } run += c1;
  if (i0+2<N_){ off[i0+2]=run; cursor[i0+2]=run; } run += c2;
  if (i0+3<N_){ off[i0+3]=run; cursor[i0+3]=run; }
}

__global__ __launch_bounds__(256) void k_scatter(const int* __restrict__ ei, int* __restrict__ cursor,
                                                 int* __restrict__ csr_src, int E_, int Et){
  int e = blockIdx.x*blockDim.x + threadIdx.x;
  if (e < Et){
    int d, s;
    if (e < E_){ s = ei[e]; d = ei[E_+e]; } else { s = e-E_; d = e-E_; }
    int pos = atomicAdd(&cursor[d], 1);
    csr_src[pos] = s;
  }
}

// ---------------- weight prep: fp32 [128k][128n] -> bf16 transposed [128n][128k] ----------------
__global__ __launch_bounds__(256) void k_prep(const float* __restrict__ W0, const float* __restrict__ W12,
                                              const float* __restrict__ Watt, unsigned short* __restrict__ dst){
  __shared__ unsigned short Lt[128*128];
  int b = blockIdx.x, t = threadIdx.x;
  const float* W = (b==0) ? W0 : (b==3 ? Watt : W12 + (size_t)(b-1)*16384);
  #pragma unroll
  for (int p=0;p<16;p++){
    int idx = p*256 + t;          // float4 id: 128 k-rows x 32 quads
    int k = idx>>5, q = idx&31;
    float4 v = ld4(&W[(size_t)k*128 + q*4]);
    Lt[(q*4+0)*128 + k] = f2bf(v.x);
    Lt[(q*4+1)*128 + k] = f2bf(v.y);
    Lt[(q*4+2)*128 + k] = f2bf(v.z);
    Lt[(q*4+3)*128 + k] = f2bf(v.w);
  }
  __syncthreads();
  unsigned short* out = dst + (size_t)b*16384;
  #pragma unroll
  for (int p=0;p<8;p++){
    int c = p*256 + t;
    *reinterpret_cast<uint4*>(&out[c*8]) = *reinterpret_cast<const uint4*>(&Lt[c*8]);
  }
}

// ---------------- MFMA bf16 GEMM  [M,128] @ [128,128] ----------------
// EPI=0: C(bf16)[m][0:128] = A@B ; EPI=1: scoresL[m*3+sc_off] = sum_c tanh((A@B)[m][c])*aatt[c]
// AF32=1: A is fp32; else A is bf16.
template<int EPI, int AF32>
__global__ __launch_bounds__(256) void k_gemm_mfma(
    const void* __restrict__ Ap, const unsigned short* __restrict__ Bt,
    unsigned short* __restrict__ C, int M,
    const float* __restrict__ aatt, float* __restrict__ scoresL, int sc_off)
{
  __shared__ unsigned short As[128*128];  // [row][k] bf16, 16B-chunk XOR-swizzled
  __shared__ unsigned short Bs[128*128];  // [col][k] bf16 (B transposed), same swizzle
  int t = threadIdx.x;
  int r0 = blockIdx.x * 128;

  // stage B (already bf16 transposed in global)
  #pragma unroll
  for (int p=0;p<8;p++){
    int c = p*256 + t;
    int row = c>>4, cb = c&15;
    uint4 v = *reinterpret_cast<const uint4*>(&Bt[c*8]);
    *reinterpret_cast<uint4*>(&Bs[row*128 + ((cb ^ (row&7))<<3)]) = v;
  }
  // stage A
  if (AF32){
    const float* A = (const float*)Ap;
    #pragma unroll
    for (int p=0;p<16;p++){
      int c = p*256 + t;
      int row = c>>5, q = c&31;
      float4 v = make_float4(0.f,0.f,0.f,0.f);
      if (r0+row < M) v = ld4(&A[(size_t)(r0+row)*128 + q*4]);
      ushort4 o; o.x=f2bf(v.x); o.y=f2bf(v.y); o.z=f2bf(v.z); o.w=f2bf(v.w);
      int cb = q>>1, half = q&1;
      *reinterpret_cast<ushort4*>(&As[row*128 + ((cb ^ (row&7))<<3) + half*4]) = o;
    }
  } else {
    const unsigned short* A = (const unsigned short*)Ap;
    #pragma unroll
    for (int p=0;p<8;p++){
      int c = p*256 + t;
      int row = c>>4, cb = c&15;
      uint4 v = make_uint4(0,0,0,0);
      if (r0+row < M) v = *reinterpret_cast<const uint4*>(&A[(size_t)(r0+row)*128 + cb*8]);
      *reinterpret_cast<uint4*>(&As[row*128 + ((cb ^ (row&7))<<3)]) = v;
    }
  }
  __syncthreads();

  int lane = t & 63, w = t >> 6;
  int rA = lane & 15, g = lane >> 4;
  int wr = w*32;
  f32x4 z = {0.f,0.f,0.f,0.f};
  f32x4 acc[2][8];
  #pragma unroll
  for (int mf=0;mf<2;mf++)
    #pragma unroll
    for (int nf=0;nf<8;nf++) acc[mf][nf] = z;

  int sx = rA & 7;
  #pragma unroll
  for (int ks=0; ks<4; ks++){
    int cbk = ks*4 + g;
    bf16x8 a[2], bfr[8];
    #pragma unroll
    for (int mf=0;mf<2;mf++){
      int row = wr + mf*16 + rA;
      a[mf] = *reinterpret_cast<const bf16x8*>(&As[row*128 + ((cbk ^ sx)<<3)]);
    }
    #pragma unroll
    for (int nf=0;nf<8;nf++){
      int col = nf*16 + rA;
      bfr[nf] = *reinterpret_cast<const bf16x8*>(&Bs[col*128 + ((cbk ^ sx)<<3)]);
    }
    #pragma unroll
    for (int mf=0;mf<2;mf++)
      #pragma unroll
      for (int nf=0;nf<8;nf++)
        acc[mf][nf] = __builtin_amdgcn_mfma_f32_16x16x32_bf16(a[mf], bfr[nf], acc[mf][nf], 0, 0, 0);
  }

  if (EPI == 0){
    #pragma unroll
    for (int mf=0;mf<2;mf++){
      #pragma unroll
      for (int r=0;r<4;r++){
        int row = r0 + wr + mf*16 + g*4 + r;
        if (row < M){
          #pragma unroll
          for (int nf=0;nf<8;nf++)
            C[(size_t)row*128 + nf*16 + rA] = f2bf(acc[mf][nf][r]);
        }
      }
    }
  } else {
    float av[8];
    #pragma unroll
    for (int nf=0;nf<8;nf++) av[nf] = aatt[nf*16 + rA];
    #pragma unroll
    for (int mf=0;mf<2;mf++){
      #pragma unroll
      for (int r=0;r<4;r++){
        float s = 0.f;
        #pragma unroll
        for (int nf=0;nf<8;nf++) s += ftanh(acc[mf][nf][r]) * av[nf];
        #pragma unroll
        for (int d=1; d<16; d<<=1) s += __shfl_xor(s, d);
        int row = r0 + wr + mf*16 + g*4 + r;
        if (rA==0 && row < M) scoresL[(size_t)row*3 + sc_off] = s;
      }
    }
  }
}

// ---------------- per-(node,head) attention dots (bf16 h) ----------------
__global__ __launch_bounds__(256) void k_sdot(const unsigned short* __restrict__ htmp,
    const float* __restrict__ a_s, const float* __restrict__ a_d,
    float* __restrict__ s_src, float* __restrict__ s_dst, int N_)
{
  int tid = blockIdx.x*blockDim.x + threadIdx.x;
  if (tid >= N_*8) return;
  int h = tid & 7;
  const unsigned short* hp = htmp + (size_t)(tid>>3)*128 + h*16;
  uint4 u0 = *reinterpret_cast<const uint4*>(hp);
  uint4 u1 = *reinterpret_cast<const uint4*>(hp+8);
  unsigned int uu[8] = {u0.x,u0.y,u0.z,u0.w,u1.x,u1.y,u1.z,u1.w};
  const float* ap = a_s + h*16;
  const float* dp = a_d + h*16;
  float ss=0.f, dd=0.f;
  #pragma unroll
  for (int q=0;q<8;q++){
    float e0 = bflo(uu[q]), e1 = bfhi(uu[q]);
    ss += e0*ap[2*q] + e1*ap[2*q+1];
    dd += e0*dp[2*q] + e1*dp[2*q+1];
  }
  s_src[tid]=ss; s_dst[tid]=dd;
}

// ---------------- wave-per-node softmax-aggregate (bf16 h in/out) ----------------
__global__ __launch_bounds__(256) void k_aggregate(
    const int* __restrict__ off, const int* __restrict__ csr_src,
    const unsigned short* __restrict__ htmp, const float* __restrict__ s_src,
    const float* __restrict__ s_dst, const float* __restrict__ bias,
    unsigned short* __restrict__ hout, int N_)
{
  __shared__ float esc[4][512];
  __shared__ int   ssrc[4][64];
  int w = threadIdx.x >> 6;
  int lane = threadIdx.x & 63;
  int n = blockIdx.x*4 + w;
  if (n >= N_) return;
  int base = off[n];
  int deg  = off[n+1] - base;
  int myh = lane >> 3;
  float4 sd0 = ld4(&s_dst[(size_t)n*8]);
  float4 sd1 = ld4(&s_dst[(size_t)n*8+4]);
  float sdv[8] = {sd0.x,sd0.y,sd0.z,sd0.w,sd1.x,sd1.y,sd1.z,sd1.w};
  float run_m[8];
  #pragma unroll
  for (int h=0;h<8;h++) run_m[h] = -1e30f;
  float acc0=0.f, acc1=0.f, dsum=0.f;

  for (int cb=0; cb<deg; cb+=64){
    int cdeg = min(64, deg-cb);
    float sc[8];
    int srcj = 0;
    if (lane < cdeg){
      srcj = csr_src[base+cb+lane];
      float4 a0 = ld4(&s_src[(size_t)srcj*8]);
      float4 a1 = ld4(&s_src[(size_t)srcj*8+4]);
      float sv[8]={a0.x,a0.y,a0.z,a0.w,a1.x,a1.y,a1.z,a1.w};
      #pragma unroll
      for (int h=0;h<8;h++){
        float v = sv[h]+sdv[h];
        sc[h] = v>0.f ? v : 0.2f*v;
      }
    } else {
      #pragma unroll
      for (int h=0;h<8;h++) sc[h] = -1e30f;
    }
    float cm[8];
    #pragma unroll
    for (int h=0;h<8;h++) cm[h]=sc[h];
    #pragma unroll
    for (int s=1;s<64;s<<=1){
      #pragma unroll
      for (int h=0;h<8;h++) cm[h] = fmaxf(cm[h], __shfl_xor(cm[h], s));
    }
    float nm[8];
    #pragma unroll
    for (int h=0;h<8;h++) nm[h] = fmaxf(run_m[h], cm[h]);
    float scale = __expf(run_m[myh] - nm[myh]);
    acc0*=scale; acc1*=scale; dsum*=scale;
    #pragma unroll
    for (int h=0;h<8;h++) run_m[h]=nm[h];

    float eev[8];
    if (lane<cdeg){
      #pragma unroll
      for (int h=0;h<8;h++) eev[h] = __expf(sc[h]-nm[h]);
    } else {
      #pragma unroll
      for (int h=0;h<8;h++) eev[h]=0.f;
    }
    *reinterpret_cast<float4*>(&esc[w][lane*8])   = make_float4(eev[0],eev[1],eev[2],eev[3]);
    *reinterpret_cast<float4*>(&esc[w][lane*8+4]) = make_float4(eev[4],eev[5],eev[6],eev[7]);
    ssrc[w][lane] = srcj;
    asm volatile("s_waitcnt lgkmcnt(0)" ::: "memory");
    __builtin_amdgcn_sched_barrier(0);

    for (int j=0;j<cdeg;j++){
      float ee = esc[w][j*8 + myh];
      int s = ssrc[w][j];
      unsigned int u = *reinterpret_cast<const unsigned int*>(&htmp[(size_t)s*128 + 2*lane]);
      acc0 = fmaf(ee, bflo(u), acc0);
      acc1 = fmaf(ee, bfhi(u), acc1);
      dsum += ee;
    }
  }
  float inv = 1.f/(dsum + 1e-16f);
  float o0 = acc0*inv + bias[2*lane];
  float o1 = acc1*inv + bias[2*lane+1];
  o0 = o0>0.f ? o0 : (__expf(o0)-1.f);
  o1 = o1>0.f ? o1 : (__expf(o1)-1.f);
  unsigned int pk = (unsigned int)f2bf(o0) | ((unsigned int)f2bf(o1)<<16);
  *reinterpret_cast<unsigned int*>(&hout[(size_t)n*128 + 2*lane]) = pk;
}

// ---------------- layer-softmax + output head ----------------
__global__ __launch_bounds__(256) void k_final(
  const unsigned short* __restrict__ h0, const unsigned short* __restrict__ h1,
  const unsigned short* __restrict__ h2,
  const float* __restrict__ scoresL, const float* __restrict__ Wout, const float* __restrict__ bout,
  float* __restrict__ out, int N_)
{
  __shared__ float hfs[4][128];
  int w = threadIdx.x>>6, lane = threadIdx.x&63;
  int n = blockIdx.x*4 + w;
  if (n>=N_) return;
  float s0 = scoresL[(size_t)n*3+0], s1 = scoresL[(size_t)n*3+1], s2 = scoresL[(size_t)n*3+2];
  float m = fmaxf(s0, fmaxf(s1,s2));
  float e0=__expf(s0-m), e1=__expf(s1-m), e2=__expf(s2-m);
  float inv = 1.f/(e0+e1+e2);
  float l0=e0*inv, l1=e1*inv, l2=e2*inv;
  unsigned int ua = *reinterpret_cast<const unsigned int*>(&h0[(size_t)n*128+2*lane]);
  unsigned int ub = *reinterpret_cast<const unsigned int*>(&h1[(size_t)n*128+2*lane]);
  unsigned int uc = *reinterpret_cast<const unsigned int*>(&h2[(size_t)n*128+2*lane]);
  hfs[w][2*lane]   = l0*bflo(ua) + l1*bflo(ub) + l2*bflo(uc);
  hfs[w][2*lane+1] = l0*bfhi(ua) + l1*bfhi(ub) + l2*bfhi(uc);
  asm volatile("s_waitcnt lgkmcnt(0)" ::: "memory");
  __builtin_amdgcn_sched_barrier(0);
  if (lane < 40){
    float accv = bout[lane];
    #pragma unroll 8
    for (int k=0;k<128;k++)
      accv = fmaf(hfs[w][k], Wout[k*40+lane], accv);
    out[(size_t)n*40 + lane] = accv;
  }
}

extern "C" void kernel_launch(void* const* d_in, const int* in_sizes, int n_in,
                              void* d_out, int out_size, void* d_ws, size_t ws_size,
                              hipStream_t stream)
{
  const float* x    = (const float*)d_in[0];
  const int*   ei   = (const int*)d_in[1];
  const float* W0   = (const float*)d_in[2];
  const float* as0  = (const float*)d_in[3];
  const float* ad0  = (const float*)d_in[4];
  const float* b0   = (const float*)d_in[5];
  const float* W12  = (const float*)d_in[6];
  const float* as12 = (const float*)d_in[7];
  const float* ad12 = (const float*)d_in[8];
  const float* b12  = (const float*)d_in[9];
  const float* Watt = (const float*)d_in[10];
  const float* aatt = (const float*)d_in[11];
  const float* Wout = (const float*)d_in[12];
  const float* bout = (const float*)d_in[13];
  const int N_ = in_sizes[0] / 128;
  const int E_ = in_sizes[1] / 2;
  const int Et = E_ + N_;

  char* p = (char*)d_ws;
  auto carve = [&](size_t bytes)->char*{ char* r = p; p += (bytes + 255) & ~(size_t)255; return r; };
  unsigned short* htmp = (unsigned short*)carve((size_t)N_*128*2);
  unsigned short* h0   = (unsigned short*)carve((size_t)N_*128*2);
  unsigned short* h1   = (unsigned short*)carve((size_t)N_*128*2);
  unsigned short* h2   = (unsigned short*)carve((size_t)N_*128*2);
  unsigned short* wsT  = (unsigned short*)carve((size_t)4*16384*2);
  float* ssrc_s  = (float*)carve((size_t)N_*8*4);
  float* sdst_s  = (float*)carve((size_t)N_*8*4);
  float* scoresL = (float*)carve((size_t)N_*3*4);
  int* cnt       = (int*)carve((size_t)N_*4);
  int* offv      = (int*)carve((size_t)(N_+1)*4);
  int* blk       = (int*)carve((size_t)64*4);
  int* blkoff    = (int*)carve((size_t)64*4);
  int* cursor    = (int*)carve((size_t)N_*4);
  int* csr       = (int*)carve((size_t)Et*4);

  k_prep<<<4,256,0,stream>>>(W0, W12, Watt, wsT);

  hipMemsetAsync(cnt, 0, (size_t)N_*4, stream);
  int gE = (Et + 255)/256;
  int nblk = (N_ + 1023)/1024;
  k_hist<<<gE,256,0,stream>>>(ei, cnt, E_, Et);
  k_scan1<<<nblk,256,0,stream>>>(cnt, blk, N_);
  k_scan2<<<1,64,0,stream>>>(blk, blkoff, offv, N_, nblk);
  k_scan3<<<nblk,256,0,stream>>>(cnt, blkoff, offv, cursor, N_);
  k_scatter<<<gE,256,0,stream>>>(ei, cursor, csr, E_, Et);

  int gM  = (N_+127)/128;
  int gS  = (N_*8+255)/256;
  int gN4 = (N_+3)/4;
  unsigned short* hl[3] = {h0,h1,h2};
  for (int l=0;l<3;l++){
    const float* as_= (l==0)? as0 : as12 + (size_t)(l-1)*128;
    const float* ad_= (l==0)? ad0 : ad12 + (size_t)(l-1)*128;
    const float* bb = (l==0)? b0  : b12  + (size_t)(l-1)*128;
    const unsigned short* Bt = wsT + (size_t)l*16384;
    if (l==0)
      k_gemm_mfma<0,1><<<gM,256,0,stream>>>(x, Bt, htmp, N_, nullptr, nullptr, 0);
    else
      k_gemm_mfma<0,0><<<gM,256,0,stream>>>(hl[l-1], Bt, htmp, N_, nullptr, nullptr, 0);
    k_sdot<<<gS,256,0,stream>>>(htmp, as_, ad_, ssrc_s, sdst_s, N_);
    k_aggregate<<<gN4,256,0,stream>>>(offv, csr, htmp, ssrc_s, sdst_s, bb, hl[l], N_);
  }
  for (int l=0;l<3;l++)
    k_gemm_mfma<1,0><<<gM,256,0,stream>>>(hl[l], wsT + (size_t)3*16384, nullptr, N_, aatt, scoresL, l);
  k_final<<<gN4,256,0,stream>>>(h0,h1,h2, scoresL, Wout, bout, (float*)d_out, N_);
}

// Round 3
// 339.846 us; speedup vs baseline: 2.0426x; 1.1788x over previous
//
#include <hip/hip_runtime.h>
#include <hip/hip_bf16.h>

typedef float f32x4 __attribute__((ext_vector_type(4)));
typedef short bf16x8 __attribute__((ext_vector_type(8)));

__device__ __forceinline__ float4 ld4(const float* p){ return *reinterpret_cast<const float4*>(p); }
__device__ __forceinline__ unsigned short f2bf(float f){
  unsigned int u = __float_as_uint(f);
  u = (u + 0x7fffu + ((u>>16)&1u)) >> 16;
  return (unsigned short)u;
}
__device__ __forceinline__ float bflo(unsigned int u){ return __uint_as_float(u<<16); }
__device__ __forceinline__ float bfhi(unsigned int u){ return __uint_as_float(u & 0xffff0000u); }
__device__ __forceinline__ float ftanh(float x){
  float e = __expf(2.f*x);
  return fmaf(-2.f, __builtin_amdgcn_rcpf(e+1.f), 1.f);
}

// =============== x fp32 -> bf16 ===============
__global__ __launch_bounds__(256) void k_xcast(const float* __restrict__ x, unsigned short* __restrict__ xb, int n8){
  int i = blockIdx.x*256 + threadIdx.x;
  if (i >= n8) return;
  float4 v0 = ld4(&x[(size_t)i*8]);
  float4 v1 = ld4(&x[(size_t)i*8+4]);
  uint4 o;
  o.x = (unsigned)f2bf(v0.x) | ((unsigned)f2bf(v0.y)<<16);
  o.y = (unsigned)f2bf(v0.z) | ((unsigned)f2bf(v0.w)<<16);
  o.z = (unsigned)f2bf(v1.x) | ((unsigned)f2bf(v1.y)<<16);
  o.w = (unsigned)f2bf(v1.z) | ((unsigned)f2bf(v1.w)<<16);
  *reinterpret_cast<uint4*>(&xb[(size_t)i*8]) = o;
}

// =============== CSR build: bucketed ===============
__global__ __launch_bounds__(256) void k_bcount(const int* __restrict__ ei, int* __restrict__ bcnt, int E_, int Et){
  __shared__ int h[64];
  int t = threadIdx.x;
  if (t < 64) h[t] = 0;
  __syncthreads();
  int e0 = blockIdx.x*2048 + t;
  #pragma unroll
  for (int k=0;k<8;k++){
    int e = e0 + k*256;
    if (e < Et){ int d = (e < E_) ? ei[E_+e] : (e-E_); atomicAdd(&h[d>>10], 1); }
  }
  __syncthreads();
  if (t < 64 && h[t]) atomicAdd(&bcnt[t], h[t]);
}

__global__ __launch_bounds__(64) void k_binit(const int* __restrict__ bcnt, int* __restrict__ bbase,
                                              int* __restrict__ bcursor, int nb){
  int l = threadIdx.x;
  int v = (l < nb) ? bcnt[l] : 0;
  int incl = v;
  #pragma unroll
  for (int d=1; d<64; d<<=1){ int u = __shfl_up(incl, d); if (l>=d) incl += u; }
  int ex = incl - v;
  if (l < nb){ bbase[l] = ex; bcursor[l] = ex; }
  if (l == 63) bbase[nb] = incl;
}

__global__ __launch_bounds__(256) void k_bucket(const int* __restrict__ ei, int* __restrict__ bcursor,
                                                uint2* __restrict__ bdata, int E_, int Et){
  __shared__ int h[64];
  __shared__ int base[64];
  int t = threadIdx.x;
  if (t < 64) h[t] = 0;
  __syncthreads();
  int e0 = blockIdx.x*2048 + t;
  int dv[8], sv[8], rv[8];
  #pragma unroll
  for (int k=0;k<8;k++){
    int e = e0 + k*256;
    if (e < Et){
      int s, d;
      if (e < E_){ s = ei[e]; d = ei[E_+e]; } else { s = e-E_; d = s; }
      dv[k] = d; sv[k] = s;
      rv[k] = atomicAdd(&h[d>>10], 1);
    } else dv[k] = -1;
  }
  __syncthreads();
  if (t < 64 && h[t]) base[t] = atomicAdd(&bcursor[t], h[t]);
  __syncthreads();
  #pragma unroll
  for (int k=0;k<8;k++){
    if (dv[k] >= 0){
      int b = dv[k]>>10;
      bdata[base[b]+rv[k]] = make_uint2((unsigned)dv[k], (unsigned)sv[k]);
    }
  }
}

__global__ __launch_bounds__(512) void k_bhist(const uint2* __restrict__ bdata, const int* __restrict__ bbase,
                                               int* __restrict__ cnt, int N_){
  __shared__ int c[1024];
  int b = blockIdx.x, t = threadIdx.x;
  for (int i=t;i<1024;i+=512) c[i]=0;
  __syncthreads();
  int lo = bbase[b], hi = bbase[b+1];
  for (int i=lo+t; i<hi; i+=512){ unsigned d = bdata[i].x; atomicAdd(&c[d&1023], 1); }
  __syncthreads();
  int n0 = b<<10;
  for (int i=t;i<1024;i+=512){ int n = n0+i; if (n < N_) cnt[n] = c[i]; }
}

__global__ __launch_bounds__(256) void k_scan1(const int* __restrict__ cnt, int* __restrict__ blk, int N_){
  int t = threadIdx.x, b = blockIdx.x;
  int i0 = b*1024 + t*4;
  int s = 0;
  if (i0+3 < N_){ int4 v = *reinterpret_cast<const int4*>(&cnt[i0]); s = v.x+v.y+v.z+v.w; }
  else { for (int j=0;j<4;j++) if (i0+j<N_) s += cnt[i0+j]; }
  #pragma unroll
  for (int d=1; d<64; d<<=1) s += __shfl_xor(s, d);
  __shared__ int ws[4];
  if ((t&63)==0) ws[t>>6] = s;
  __syncthreads();
  if (t==0) blk[b] = ws[0]+ws[1]+ws[2]+ws[3];
}

__global__ __launch_bounds__(64) void k_scan2(const int* __restrict__ blk, int* __restrict__ blkoff,
                                              int* __restrict__ off, int N_, int nblk){
  int l = threadIdx.x;
  int v = (l<nblk)? blk[l] : 0;
  int incl = v;
  #pragma unroll
  for (int d=1; d<64; d<<=1){ int u = __shfl_up(incl, d); if (l>=d) incl += u; }
  if (l<nblk) blkoff[l] = incl - v;
  if (l==63) off[N_] = incl;
}

__global__ __launch_bounds__(256) void k_scan3(const int* __restrict__ cnt, const int* __restrict__ blkoff,
                                               int* __restrict__ off, int N_){
  int t = threadIdx.x, b = blockIdx.x;
  int i0 = b*1024 + t*4;
  int c0=0,c1=0,c2=0,c3=0;
  if (i0+3 < N_){ int4 v = *reinterpret_cast<const int4*>(&cnt[i0]); c0=v.x;c1=v.y;c2=v.z;c3=v.w; }
  else { if(i0<N_)c0=cnt[i0]; if(i0+1<N_)c1=cnt[i0+1]; if(i0+2<N_)c2=cnt[i0+2]; if(i0+3<N_)c3=cnt[i0+3]; }
  int s = c0+c1+c2+c3;
  int incl = s;
  int lane = t&63, w = t>>6;
  #pragma unroll
  for (int d=1; d<64; d<<=1){ int u = __shfl_up(incl, d); if (lane>=d) incl += u; }
  __shared__ int ws[4];
  if (lane==63) ws[w] = incl;
  __syncthreads();
  int wpre = 0;
  #pragma unroll
  for (int k=0;k<4;k++) if (k<w) wpre += ws[k];
  int run = blkoff[b] + wpre + incl - s;
  if (i0  <N_) off[i0]   = run; run += c0;
  if (i0+1<N_) off[i0+1] = run; run += c1;
  if (i0+2<N_) off[i0+2] = run; run += c2;
  if (i0+3<N_) off[i0+3] = run;
}

__global__ __launch_bounds__(512) void k_bscatter(const uint2* __restrict__ bdata, const int* __restrict__ bbase,
                                                  const int* __restrict__ off, int* __restrict__ csr, int N_){
  __shared__ int cur[1024];
  int b = blockIdx.x, t = threadIdx.x;
  int n0 = b<<10;
  for (int i=t;i<1024;i+=512){ int n = n0+i; cur[i] = (n < N_) ? off[n] : 0; }
  __syncthreads();
  int lo = bbase[b], hi = bbase[b+1];
  for (int i=lo+t; i<hi; i+=512){
    uint2 p = bdata[i];
    int pos = atomicAdd(&cur[p.x & 1023], 1);
    csr[pos] = (int)p.y;
  }
}

// =============== weight prep: W fp32 -> Bt bf16 [144 cols][128 k], cols 128..143 = [Ws|Wd] ===============
__global__ __launch_bounds__(256) void k_prep(const float* __restrict__ W0, const float* __restrict__ W12,
    const float* __restrict__ Watt, const float* __restrict__ as0, const float* __restrict__ ad0,
    const float* __restrict__ as12, const float* __restrict__ ad12, unsigned short* __restrict__ dst){
  __shared__ float Wf[64*128];
  int b = blockIdx.x, t = threadIdx.x;
  const float* W = (b==0) ? W0 : (b==3 ? Watt : W12 + (size_t)(b-1)*16384);
  unsigned short* out = dst + (size_t)b*18432;
  const float* as_ = (b==0) ? as0 : as12 + (size_t)(b-1)*128;
  const float* ad_ = (b==0) ? ad0 : ad12 + (size_t)(b-1)*128;

  for (int half=0; half<2; half++){
    // stage 64 k-rows of W in fp32
    #pragma unroll
    for (int p=0;p<8;p++){
      int i = p*256 + t;                     // float4 index within 64x128
      *reinterpret_cast<float4*>(&Wf[i*4]) = ld4(&W[(size_t)half*8192 + i*4]);
    }
    __syncthreads();
    // main transposed cols
    {
      int col = t>>1, koff = (t&1)*32;
      #pragma unroll
      for (int j=0;j<4;j++){
        unsigned short tmp[8];
        #pragma unroll
        for (int q=0;q<8;q++) tmp[q] = f2bf(Wf[(koff + j*8 + q)*128 + col]);
        *reinterpret_cast<uint4*>(&out[col*128 + half*64 + koff + j*8]) = *reinterpret_cast<const uint4*>(tmp);
      }
    }
    // extra cols 128..143: Ws (0..7), Wd (8..15)
    {
      int ce = t>>4;          // 0..15
      int h  = ce & 7;
      if (b < 3){
        const float* av = (ce < 8) ? (as_ + h*16) : (ad_ + h*16);
        float avr[16];
        #pragma unroll
        for (int c2=0;c2<16;c2++) avr[c2] = av[c2];
        #pragma unroll
        for (int i=0;i<4;i++){
          int kl = (t&15) + i*16;
          float s = 0.f;
          #pragma unroll
          for (int c2=0;c2<16;c2++) s += Wf[kl*128 + h*16 + c2]*avr[c2];
          out[(128+ce)*128 + half*64 + kl] = f2bf(s);
        }
      } else {
        #pragma unroll
        for (int i=0;i<4;i++){
          int kl = (t&15) + i*16;
          out[(128+ce)*128 + half*64 + kl] = 0;
        }
      }
    }
    __syncthreads();
  }
}

// =============== MFMA GEMM (no LDS): A[M,128]bf16 @ Bt[144,128]bf16 ===============
// EPI=0: C=A@B (bf16) + s_src/s_dst from cols 128..143 ; EPI=1: scoresL[m*3+off] = sum tanh(.)*aatt
template<int EPI>
__global__ __launch_bounds__(256) void k_gemm(
    const unsigned short* __restrict__ A, const unsigned short* __restrict__ Bt,
    unsigned short* __restrict__ C, float* __restrict__ s_src, float* __restrict__ s_dst, int M,
    const float* __restrict__ aatt, float* __restrict__ scoresL, int sc_off)
{
  constexpr int NF = (EPI==0) ? 9 : 8;
  int t = threadIdx.x, lane = t & 63, w = t >> 6;
  int rA = lane & 15, g = lane >> 4;
  int r0 = blockIdx.x*128 + w*32;
  f32x4 z = {0.f,0.f,0.f,0.f};
  f32x4 acc[2][NF];
  #pragma unroll
  for (int mf=0;mf<2;mf++)
    #pragma unroll
    for (int nf=0;nf<NF;nf++) acc[mf][nf] = z;

  int rowc0 = min(r0 + rA,      M-1);
  int rowc1 = min(r0 + 16 + rA, M-1);
  #pragma unroll
  for (int ks=0; ks<4; ks++){
    int ko = ks*32 + g*8;
    bf16x8 a0 = *reinterpret_cast<const bf16x8*>(A + (size_t)rowc0*128 + ko);
    bf16x8 a1 = *reinterpret_cast<const bf16x8*>(A + (size_t)rowc1*128 + ko);
    #pragma unroll
    for (int nf=0;nf<NF;nf++){
      bf16x8 bf_ = *reinterpret_cast<const bf16x8*>(Bt + (size_t)(nf*16+rA)*128 + ko);
      acc[0][nf] = __builtin_amdgcn_mfma_f32_16x16x32_bf16(a0, bf_, acc[0][nf], 0, 0, 0);
      acc[1][nf] = __builtin_amdgcn_mfma_f32_16x16x32_bf16(a1, bf_, acc[1][nf], 0, 0, 0);
    }
  }

  if (EPI == 0){
    #pragma unroll
    for (int mf=0;mf<2;mf++){
      #pragma unroll
      for (int r=0;r<4;r++){
        int row = r0 + mf*16 + g*4 + r;
        if (row < M){
          #pragma unroll
          for (int nf=0;nf<8;nf++) C[(size_t)row*128 + nf*16 + rA] = f2bf(acc[mf][nf][r]);
          float sv_ = acc[mf][8][r];
          if (rA < 8) s_src[(size_t)row*8 + rA]     = sv_;
          else        s_dst[(size_t)row*8 + rA - 8] = sv_;
        }
      }
    }
  } else {
    float av[8];
    #pragma unroll
    for (int nf=0;nf<8;nf++) av[nf] = aatt[nf*16 + rA];
    #pragma unroll
    for (int mf=0;mf<2;mf++){
      #pragma unroll
      for (int r=0;r<4;r++){
        float s = 0.f;
        #pragma unroll
        for (int nf=0;nf<8;nf++) s += ftanh(acc[mf][nf][r]) * av[nf];
        s += __shfl_xor(s, 1);
        s += __shfl_xor(s, 2);
        s += __shfl_xor(s, 4);
        s += __shfl_xor(s, 8);
        int row = r0 + mf*16 + g*4 + r;
        if (rA==0 && row < M) scoresL[(size_t)row*3 + sc_off] = s;
      }
    }
  }
}

// =============== wave-per-node softmax-aggregate ===============
__global__ __launch_bounds__(256) void k_aggregate(
    const int* __restrict__ off, const int* __restrict__ csr,
    const unsigned short* __restrict__ htmp, const float* __restrict__ s_src,
    const float* __restrict__ s_dst, const float* __restrict__ bias,
    unsigned short* __restrict__ hout, int N_)
{
  __shared__ float esc[4][544];   // [head*68 + edge]
  __shared__ int   ssrc[4][64];
  int w = threadIdx.x >> 6;
  int lane = threadIdx.x & 63;
  int n = blockIdx.x*4 + w;
  if (n >= N_) return;
  int base = off[n];
  int deg  = off[n+1] - base;
  int c  = lane & 31;       // 4 channels: 4c..4c+3
  int eo = lane >> 5;       // edge parity
  int myh = c >> 2;         // head of my channels
  float4 sd0 = ld4(&s_dst[(size_t)n*8]);
  float4 sd1 = ld4(&s_dst[(size_t)n*8+4]);
  float sdv[8] = {sd0.x,sd0.y,sd0.z,sd0.w,sd1.x,sd1.y,sd1.z,sd1.w};
  float acc0=0.f, acc1=0.f, acc2=0.f, acc3=0.f, dsum=0.f;
  const char* hb = (const char*)htmp + (c<<3);

  for (int cb=0; cb<deg; cb+=64){
    int cdeg = min(64, deg-cb);
    int srcj = 0;
    float ee[8];
    if (lane < cdeg){
      srcj = csr[base+cb+lane];
      float4 a0 = ld4(&s_src[(size_t)srcj*8]);
      float4 a1 = ld4(&s_src[(size_t)srcj*8+4]);
      float sv[8] = {a0.x,a0.y,a0.z,a0.w,a1.x,a1.y,a1.z,a1.w};
      #pragma unroll
      for (int h=0;h<8;h++){
        float v = sv[h] + sdv[h];
        v = v > 0.f ? v : 0.2f*v;
        ee[h] = __expf(v);
      }
    } else {
      #pragma unroll
      for (int h=0;h<8;h++) ee[h] = 0.f;
    }
    ssrc[w][lane] = srcj;
    #pragma unroll
    for (int h=0;h<8;h++) esc[w][h*68 + lane] = ee[h];
    asm volatile("s_waitcnt lgkmcnt(0)" ::: "memory");
    __builtin_amdgcn_sched_barrier(0);

    for (int j=0; j<cdeg; j+=4){
      int s0 = ssrc[w][j+eo];
      int s1 = ssrc[w][j+2+eo];
      float e0 = esc[w][myh*68 + j+eo];
      float e1 = esc[w][myh*68 + j+2+eo];
      uint2 u0 = *reinterpret_cast<const uint2*>(hb + ((unsigned)s0<<8));
      uint2 u1 = *reinterpret_cast<const uint2*>(hb + ((unsigned)s1<<8));
      acc0 = fmaf(e0, bflo(u0.x), acc0);
      acc1 = fmaf(e0, bfhi(u0.x), acc1);
      acc2 = fmaf(e0, bflo(u0.y), acc2);
      acc3 = fmaf(e0, bfhi(u0.y), acc3);
      acc0 = fmaf(e1, bflo(u1.x), acc0);
      acc1 = fmaf(e1, bfhi(u1.x), acc1);
      acc2 = fmaf(e1, bflo(u1.y), acc2);
      acc3 = fmaf(e1, bfhi(u1.y), acc3);
      dsum += e0 + e1;
    }
  }
  // merge the two edge-parity halves
  acc0 += __shfl_xor(acc0, 32);
  acc1 += __shfl_xor(acc1, 32);
  acc2 += __shfl_xor(acc2, 32);
  acc3 += __shfl_xor(acc3, 32);
  dsum += __shfl_xor(dsum, 32);

  float inv = 1.f/(dsum + 1e-16f);
  float4 bv = ld4(&bias[c*4]);
  float o0 = fmaf(acc0, inv, bv.x);
  float o1 = fmaf(acc1, inv, bv.y);
  float o2 = fmaf(acc2, inv, bv.z);
  float o3 = fmaf(acc3, inv, bv.w);
  o0 = o0>0.f ? o0 : (__expf(o0)-1.f);
  o1 = o1>0.f ? o1 : (__expf(o1)-1.f);
  o2 = o2>0.f ? o2 : (__expf(o2)-1.f);
  o3 = o3>0.f ? o3 : (__expf(o3)-1.f);
  if (eo == 0){
    unsigned lo = (unsigned)f2bf(o0) | ((unsigned)f2bf(o1)<<16);
    unsigned hi = (unsigned)f2bf(o2) | ((unsigned)f2bf(o3)<<16);
    *reinterpret_cast<uint2*>(&hout[(size_t)n*128 + c*4]) = make_uint2(lo, hi);
  }
}

// =============== layer-softmax + output head ===============
__global__ __launch_bounds__(256) void k_final(
  const unsigned short* __restrict__ h0, const unsigned short* __restrict__ h1,
  const unsigned short* __restrict__ h2,
  const float* __restrict__ scoresL, const float* __restrict__ Wout, const float* __restrict__ bout,
  float* __restrict__ out, int N_)
{
  __shared__ float hfs[4][128];
  int w = threadIdx.x>>6, lane = threadIdx.x&63;
  int n = blockIdx.x*4 + w;
  if (n>=N_) return;
  float s0 = scoresL[(size_t)n*3+0], s1 = scoresL[(size_t)n*3+1], s2 = scoresL[(size_t)n*3+2];
  float m = fmaxf(s0, fmaxf(s1,s2));
  float e0=__expf(s0-m), e1=__expf(s1-m), e2=__expf(s2-m);
  float inv = 1.f/(e0+e1+e2);
  float l0=e0*inv, l1=e1*inv, l2=e2*inv;
  unsigned int ua = *reinterpret_cast<const unsigned int*>(&h0[(size_t)n*128+2*lane]);
  unsigned int ub = *reinterpret_cast<const unsigned int*>(&h1[(size_t)n*128+2*lane]);
  unsigned int uc = *reinterpret_cast<const unsigned int*>(&h2[(size_t)n*128+2*lane]);
  hfs[w][2*lane]   = l0*bflo(ua) + l1*bflo(ub) + l2*bflo(uc);
  hfs[w][2*lane+1] = l0*bfhi(ua) + l1*bfhi(ub) + l2*bfhi(uc);
  asm volatile("s_waitcnt lgkmcnt(0)" ::: "memory");
  __builtin_amdgcn_sched_barrier(0);
  if (lane < 40){
    float accv = bout[lane];
    #pragma unroll 8
    for (int k=0;k<128;k++)
      accv = fmaf(hfs[w][k], Wout[k*40+lane], accv);
    out[(size_t)n*40 + lane] = accv;
  }
}

extern "C" void kernel_launch(void* const* d_in, const int* in_sizes, int n_in,
                              void* d_out, int out_size, void* d_ws, size_t ws_size,
                              hipStream_t stream)
{
  const float* x    = (const float*)d_in[0];
  const int*   ei   = (const int*)d_in[1];
  const float* W0   = (const float*)d_in[2];
  const float* as0  = (const float*)d_in[3];
  const float* ad0  = (const float*)d_in[4];
  const float* b0   = (const float*)d_in[5];
  const float* W12  = (const float*)d_in[6];
  const float* as12 = (const float*)d_in[7];
  const float* ad12 = (const float*)d_in[8];
  const float* b12  = (const float*)d_in[9];
  const float* Watt = (const float*)d_in[10];
  const float* aatt = (const float*)d_in[11];
  const float* Wout = (const float*)d_in[12];
  const float* bout = (const float*)d_in[13];
  const int N_ = in_sizes[0] / 128;
  const int E_ = in_sizes[1] / 2;
  const int Et = E_ + N_;
  const int nb = (N_ + 1023) >> 10;

  char* p = (char*)d_ws;
  auto carve = [&](size_t bytes)->char*{ char* r = p; p += (bytes + 255) & ~(size_t)255; return r; };
  unsigned short* xb   = (unsigned short*)carve((size_t)N_*128*2);
  unsigned short* htmp = (unsigned short*)carve((size_t)N_*128*2);
  unsigned short* h0   = (unsigned short*)carve((size_t)N_*128*2);
  unsigned short* h1   = (unsigned short*)carve((size_t)N_*128*2);
  unsigned short* h2   = (unsigned short*)carve((size_t)N_*128*2);
  unsigned short* wsT  = (unsigned short*)carve((size_t)4*18432*2);
  float* ssrc_s  = (float*)carve((size_t)N_*8*4);
  float* sdst_s  = (float*)carve((size_t)N_*8*4);
  float* scoresL = (float*)carve((size_t)N_*3*4);
  int* cnt       = (int*)carve((size_t)N_*4);
  int* offv      = (int*)carve((size_t)(N_+1)*4);
  int* blk       = (int*)carve((size_t)64*4);
  int* blkoff    = (int*)carve((size_t)64*4);
  int* bcnt      = (int*)carve((size_t)64*4);
  int* bbase     = (int*)carve((size_t)66*4);
  int* bcursor   = (int*)carve((size_t)64*4);
  uint2* bdata   = (uint2*)carve((size_t)Et*8);
  int* csr       = (int*)carve((size_t)Et*4);

  k_prep<<<4,256,0,stream>>>(W0, W12, Watt, as0, ad0, as12, ad12, wsT);
  k_xcast<<<(N_*128/8 + 255)/256,256,0,stream>>>(x, xb, N_*128/8);

  hipMemsetAsync(bcnt, 0, 64*4, stream);
  int gB = (Et + 2047)/2048;
  k_bcount<<<gB,256,0,stream>>>(ei, bcnt, E_, Et);
  k_binit<<<1,64,0,stream>>>(bcnt, bbase, bcursor, nb);
  k_bucket<<<gB,256,0,stream>>>(ei, bcursor, bdata, E_, Et);
  k_bhist<<<nb,512,0,stream>>>(bdata, bbase, cnt, N_);
  int nblk = (N_ + 1023)/1024;
  k_scan1<<<nblk,256,0,stream>>>(cnt, blk, N_);
  k_scan2<<<1,64,0,stream>>>(blk, blkoff, offv, N_, nblk);
  k_scan3<<<nblk,256,0,stream>>>(cnt, blkoff, offv, N_);
  k_bscatter<<<nb,512,0,stream>>>(bdata, bbase, offv, csr, N_);

  int gM  = (N_+127)/128;
  int gN4 = (N_+3)/4;
  unsigned short* hl[3] = {h0,h1,h2};
  const unsigned short* hin = xb;
  for (int l=0;l<3;l++){
    const float* bb = (l==0)? b0 : b12 + (size_t)(l-1)*128;
    const unsigned short* Bt = wsT + (size_t)l*18432;
    k_gemm<0><<<gM,256,0,stream>>>(hin, Bt, htmp, ssrc_s, sdst_s, N_, nullptr, nullptr, 0);
    k_aggregate<<<gN4,256,0,stream>>>(offv, csr, htmp, ssrc_s, sdst_s, bb, hl[l], N_);
    hin = hl[l];
  }
  for (int l=0;l<3;l++)
    k_gemm<1><<<gM,256,0,stream>>>(hl[l], wsT + (size_t)3*18432, nullptr, nullptr, nullptr, N_, aatt, scoresL, l);
  k_final<<<gN4,256,0,stream>>>(h0,h1,h2, scoresL, Wout, bout, (float*)d_out, N_);
}

// Round 4
// 293.880 us; speedup vs baseline: 2.3620x; 1.1564x over previous
//
#include <hip/hip_runtime.h>
#include <hip/hip_bf16.h>

typedef float f32x4 __attribute__((ext_vector_type(4)));
typedef short bf16x8 __attribute__((ext_vector_type(8)));

__device__ __forceinline__ float4 ld4(const float* p){ return *reinterpret_cast<const float4*>(p); }
__device__ __forceinline__ unsigned short f2bf(float f){
  unsigned int u = __float_as_uint(f);
  u = (u + 0x7fffu + ((u>>16)&1u)) >> 16;
  return (unsigned short)u;
}
__device__ __forceinline__ float bflo(unsigned int u){ return __uint_as_float(u<<16); }
__device__ __forceinline__ float bfhi(unsigned int u){ return __uint_as_float(u & 0xffff0000u); }
__device__ __forceinline__ float ftanh(float x){
  float e = __expf(2.f*x);
  return fmaf(-2.f, __builtin_amdgcn_rcpf(e+1.f), 1.f);
}

// =============== x fp32 -> bf16 ===============
__global__ __launch_bounds__(256) void k_xcast(const float* __restrict__ x, unsigned short* __restrict__ xb, int n8){
  int i = blockIdx.x*256 + threadIdx.x;
  if (i >= n8) return;
  float4 v0 = ld4(&x[(size_t)i*8]);
  float4 v1 = ld4(&x[(size_t)i*8+4]);
  uint4 o;
  o.x = (unsigned)f2bf(v0.x) | ((unsigned)f2bf(v0.y)<<16);
  o.y = (unsigned)f2bf(v0.z) | ((unsigned)f2bf(v0.w)<<16);
  o.z = (unsigned)f2bf(v1.x) | ((unsigned)f2bf(v1.y)<<16);
  o.w = (unsigned)f2bf(v1.z) | ((unsigned)f2bf(v1.w)<<16);
  *reinterpret_cast<uint4*>(&xb[(size_t)i*8]) = o;
}

// =============== CSR build: bucketed ===============
__global__ __launch_bounds__(256) void k_bcount(const int* __restrict__ ei, int* __restrict__ bcnt, int E_, int Et){
  __shared__ int h[64];
  int t = threadIdx.x;
  if (t < 64) h[t] = 0;
  __syncthreads();
  int e0 = blockIdx.x*2048 + t;
  #pragma unroll
  for (int k=0;k<8;k++){
    int e = e0 + k*256;
    if (e < Et){ int d = (e < E_) ? ei[E_+e] : (e-E_); atomicAdd(&h[d>>10], 1); }
  }
  __syncthreads();
  if (t < 64 && h[t]) atomicAdd(&bcnt[t], h[t]);
}

__global__ __launch_bounds__(64) void k_binit(const int* __restrict__ bcnt, int* __restrict__ bbase,
                                              int* __restrict__ bcursor, int nb){
  int l = threadIdx.x;
  int v = (l < nb) ? bcnt[l] : 0;
  int incl = v;
  #pragma unroll
  for (int d=1; d<64; d<<=1){ int u = __shfl_up(incl, d); if (l>=d) incl += u; }
  int ex = incl - v;
  if (l < nb){ bbase[l] = ex; bcursor[l] = ex; }
  if (l == 63) bbase[nb] = incl;
}

__global__ __launch_bounds__(256) void k_bucket(const int* __restrict__ ei, int* __restrict__ bcursor,
                                                uint2* __restrict__ bdata, int E_, int Et){
  __shared__ int h[64];
  __shared__ int base[64];
  int t = threadIdx.x;
  if (t < 64) h[t] = 0;
  __syncthreads();
  int e0 = blockIdx.x*2048 + t;
  int dv[8], sv[8], rv[8];
  #pragma unroll
  for (int k=0;k<8;k++){
    int e = e0 + k*256;
    if (e < Et){
      int s, d;
      if (e < E_){ s = ei[e]; d = ei[E_+e]; } else { s = e-E_; d = s; }
      dv[k] = d; sv[k] = s;
      rv[k] = atomicAdd(&h[d>>10], 1);
    } else dv[k] = -1;
  }
  __syncthreads();
  if (t < 64 && h[t]) base[t] = atomicAdd(&bcursor[t], h[t]);
  __syncthreads();
  #pragma unroll
  for (int k=0;k<8;k++){
    if (dv[k] >= 0){
      int b = dv[k]>>10;
      bdata[base[b]+rv[k]] = make_uint2((unsigned)dv[k], (unsigned)sv[k]);
    }
  }
}

__global__ __launch_bounds__(512) void k_bhist(const uint2* __restrict__ bdata, const int* __restrict__ bbase,
                                               int* __restrict__ cnt, int N_){
  __shared__ int c[1024];
  int b = blockIdx.x, t = threadIdx.x;
  for (int i=t;i<1024;i+=512) c[i]=0;
  __syncthreads();
  int lo = bbase[b], hi = bbase[b+1];
  for (int i=lo+t; i<hi; i+=512){ unsigned d = bdata[i].x; atomicAdd(&c[d&1023], 1); }
  __syncthreads();
  int n0 = b<<10;
  for (int i=t;i<1024;i+=512){ int n = n0+i; if (n < N_) cnt[n] = c[i]; }
}

__global__ __launch_bounds__(256) void k_scan1(const int* __restrict__ cnt, int* __restrict__ blk, int N_){
  int t = threadIdx.x, b = blockIdx.x;
  int i0 = b*1024 + t*4;
  int s = 0;
  if (i0+3 < N_){ int4 v = *reinterpret_cast<const int4*>(&cnt[i0]); s = v.x+v.y+v.z+v.w; }
  else { for (int j=0;j<4;j++) if (i0+j<N_) s += cnt[i0+j]; }
  #pragma unroll
  for (int d=1; d<64; d<<=1) s += __shfl_xor(s, d);
  __shared__ int ws[4];
  if ((t&63)==0) ws[t>>6] = s;
  __syncthreads();
  if (t==0) blk[b] = ws[0]+ws[1]+ws[2]+ws[3];
}

__global__ __launch_bounds__(64) void k_scan2(const int* __restrict__ blk, int* __restrict__ blkoff,
                                              int* __restrict__ off, int N_, int nblk){
  int l = threadIdx.x;
  int v = (l<nblk)? blk[l] : 0;
  int incl = v;
  #pragma unroll
  for (int d=1; d<64; d<<=1){ int u = __shfl_up(incl, d); if (l>=d) incl += u; }
  if (l<nblk) blkoff[l] = incl - v;
  if (l==63) off[N_] = incl;
}

__global__ __launch_bounds__(256) void k_scan3(const int* __restrict__ cnt, const int* __restrict__ blkoff,
                                               int* __restrict__ off, int N_){
  int t = threadIdx.x, b = blockIdx.x;
  int i0 = b*1024 + t*4;
  int c0=0,c1=0,c2=0,c3=0;
  if (i0+3 < N_){ int4 v = *reinterpret_cast<const int4*>(&cnt[i0]); c0=v.x;c1=v.y;c2=v.z;c3=v.w; }
  else { if(i0<N_)c0=cnt[i0]; if(i0+1<N_)c1=cnt[i0+1]; if(i0+2<N_)c2=cnt[i0+2]; if(i0+3<N_)c3=cnt[i0+3]; }
  int s = c0+c1+c2+c3;
  int incl = s;
  int lane = t&63, w = t>>6;
  #pragma unroll
  for (int d=1; d<64; d<<=1){ int u = __shfl_up(incl, d); if (lane>=d) incl += u; }
  __shared__ int ws[4];
  if (lane==63) ws[w] = incl;
  __syncthreads();
  int wpre = 0;
  #pragma unroll
  for (int k=0;k<4;k++) if (k<w) wpre += ws[k];
  int run = blkoff[b] + wpre + incl - s;
  if (i0  <N_) off[i0]   = run; run += c0;
  if (i0+1<N_) off[i0+1] = run; run += c1;
  if (i0+2<N_) off[i0+2] = run; run += c2;
  if (i0+3<N_) off[i0+3] = run;
}

__global__ __launch_bounds__(512) void k_bscatter(const uint2* __restrict__ bdata, const int* __restrict__ bbase,
                                                  const int* __restrict__ off, int* __restrict__ csr, int N_){
  __shared__ int cur[1024];
  int b = blockIdx.x, t = threadIdx.x;
  int n0 = b<<10;
  for (int i=t;i<1024;i+=512){ int n = n0+i; cur[i] = (n < N_) ? off[n] : 0; }
  __syncthreads();
  int lo = bbase[b], hi = bbase[b+1];
  for (int i=lo+t; i<hi; i+=512){
    uint2 p = bdata[i];
    int pos = atomicAdd(&cur[p.x & 1023], 1);
    csr[pos] = (int)p.y;
  }
}

// =============== weight prep: W fp32 -> Bt bf16 [144 cols][128 k], cols 128..143 = [Ws|Wd] ===============
__global__ __launch_bounds__(256) void k_prep(const float* __restrict__ W0, const float* __restrict__ W12,
    const float* __restrict__ Watt, const float* __restrict__ as0, const float* __restrict__ ad0,
    const float* __restrict__ as12, const float* __restrict__ ad12, unsigned short* __restrict__ dst){
  __shared__ float Wf[64*128];
  int b = blockIdx.x, t = threadIdx.x;
  const float* W = (b==0) ? W0 : (b==3 ? Watt : W12 + (size_t)(b-1)*16384);
  unsigned short* out = dst + (size_t)b*18432;
  const float* as_ = (b==0) ? as0 : as12 + (size_t)(b-1)*128;
  const float* ad_ = (b==0) ? ad0 : ad12 + (size_t)(b-1)*128;

  for (int half=0; half<2; half++){
    #pragma unroll
    for (int p=0;p<8;p++){
      int i = p*256 + t;
      *reinterpret_cast<float4*>(&Wf[i*4]) = ld4(&W[(size_t)half*8192 + i*4]);
    }
    __syncthreads();
    {
      int col = t>>1, koff = (t&1)*32;
      #pragma unroll
      for (int j=0;j<4;j++){
        unsigned short tmp[8];
        #pragma unroll
        for (int q=0;q<8;q++) tmp[q] = f2bf(Wf[(koff + j*8 + q)*128 + col]);
        *reinterpret_cast<uint4*>(&out[col*128 + half*64 + koff + j*8]) = *reinterpret_cast<const uint4*>(tmp);
      }
    }
    {
      int ce = t>>4;
      int h  = ce & 7;
      if (b < 3){
        const float* av = (ce < 8) ? (as_ + h*16) : (ad_ + h*16);
        float avr[16];
        #pragma unroll
        for (int c2=0;c2<16;c2++) avr[c2] = av[c2];
        #pragma unroll
        for (int i=0;i<4;i++){
          int kl = (t&15) + i*16;
          float s = 0.f;
          #pragma unroll
          for (int c2=0;c2<16;c2++) s += Wf[kl*128 + h*16 + c2]*avr[c2];
          out[(128+ce)*128 + half*64 + kl] = f2bf(s);
        }
      } else {
        #pragma unroll
        for (int i=0;i<4;i++){
          int kl = (t&15) + i*16;
          out[(128+ce)*128 + half*64 + kl] = 0;
        }
      }
    }
    __syncthreads();
  }
}

// =============== Wout prep: fp32 [128k][40] -> bf16 hi/lo [48 cols][128 k] ===============
__global__ __launch_bounds__(256) void k_prep_out(const float* __restrict__ Wout, unsigned short* __restrict__ dst){
  int t = threadIdx.x;
  for (int i=t; i<48*128; i+=256){
    int col = i>>7, k = i&127;
    float v = (col < 40) ? Wout[(size_t)k*40 + col] : 0.f;
    unsigned short hi = f2bf(v);
    float r = v - __uint_as_float(((unsigned)hi)<<16);
    dst[i] = hi;
    dst[48*128 + i] = f2bf(r);
  }
}

// =============== MFMA GEMM (no LDS): A[M,128]bf16 @ Bt[144,128]bf16 ===============
// C=A@B (bf16) + s_src/s_dst from cols 128..143
__global__ __launch_bounds__(256) void k_gemm(
    const unsigned short* __restrict__ A, const unsigned short* __restrict__ Bt,
    unsigned short* __restrict__ C, float* __restrict__ s_src, float* __restrict__ s_dst, int M)
{
  int t = threadIdx.x, lane = t & 63, w = t >> 6;
  int rA = lane & 15, g = lane >> 4;
  int r0 = blockIdx.x*128 + w*32;
  f32x4 z = {0.f,0.f,0.f,0.f};
  f32x4 acc[2][9];
  #pragma unroll
  for (int mf=0;mf<2;mf++)
    #pragma unroll
    for (int nf=0;nf<9;nf++) acc[mf][nf] = z;

  int rowc0 = min(r0 + rA,      M-1);
  int rowc1 = min(r0 + 16 + rA, M-1);
  #pragma unroll
  for (int ks=0; ks<4; ks++){
    int ko = ks*32 + g*8;
    bf16x8 a0 = *reinterpret_cast<const bf16x8*>(A + (size_t)rowc0*128 + ko);
    bf16x8 a1 = *reinterpret_cast<const bf16x8*>(A + (size_t)rowc1*128 + ko);
    #pragma unroll
    for (int nf=0;nf<9;nf++){
      bf16x8 bf_ = *reinterpret_cast<const bf16x8*>(Bt + (size_t)(nf*16+rA)*128 + ko);
      acc[0][nf] = __builtin_amdgcn_mfma_f32_16x16x32_bf16(a0, bf_, acc[0][nf], 0, 0, 0);
      acc[1][nf] = __builtin_amdgcn_mfma_f32_16x16x32_bf16(a1, bf_, acc[1][nf], 0, 0, 0);
    }
  }

  #pragma unroll
  for (int mf=0;mf<2;mf++){
    #pragma unroll
    for (int r=0;r<4;r++){
      int row = r0 + mf*16 + g*4 + r;
      if (row < M){
        #pragma unroll
        for (int nf=0;nf<8;nf++) C[(size_t)row*128 + nf*16 + rA] = f2bf(acc[mf][nf][r]);
        float sv_ = acc[mf][8][r];
        if (rA < 8) s_src[(size_t)row*8 + rA]     = sv_;
        else        s_dst[(size_t)row*8 + rA - 8] = sv_;
      }
    }
  }
}

// =============== wave-per-node softmax-aggregate ===============
__global__ __launch_bounds__(256) void k_aggregate(
    const int* __restrict__ off, const int* __restrict__ csr,
    const unsigned short* __restrict__ htmp, const float* __restrict__ s_src,
    const float* __restrict__ s_dst, const float* __restrict__ bias,
    unsigned short* __restrict__ hout, int N_)
{
  __shared__ float esc[4][544];   // [head*68 + edge]
  __shared__ int   ssrc[4][64];
  int w = threadIdx.x >> 6;
  int lane = threadIdx.x & 63;
  int n = blockIdx.x*4 + w;
  if (n >= N_) return;
  int base = off[n];
  int deg  = off[n+1] - base;
  int c  = lane & 31;
  int eo = lane >> 5;
  int myh = c >> 2;
  float4 sd0 = ld4(&s_dst[(size_t)n*8]);
  float4 sd1 = ld4(&s_dst[(size_t)n*8+4]);
  float sdv[8] = {sd0.x,sd0.y,sd0.z,sd0.w,sd1.x,sd1.y,sd1.z,sd1.w};
  float acc0=0.f, acc1=0.f, acc2=0.f, acc3=0.f, dsum=0.f;
  const char* hb = (const char*)htmp + (c<<3);

  for (int cb=0; cb<deg; cb+=64){
    int cdeg = min(64, deg-cb);
    int srcj = 0;
    float ee[8];
    if (lane < cdeg){
      srcj = csr[base+cb+lane];
      float4 a0 = ld4(&s_src[(size_t)srcj*8]);
      float4 a1 = ld4(&s_src[(size_t)srcj*8+4]);
      float sv[8] = {a0.x,a0.y,a0.z,a0.w,a1.x,a1.y,a1.z,a1.w};
      #pragma unroll
      for (int h=0;h<8;h++){
        float v = sv[h] + sdv[h];
        v = v > 0.f ? v : 0.2f*v;
        ee[h] = __expf(v);
      }
    } else {
      #pragma unroll
      for (int h=0;h<8;h++) ee[h] = 0.f;
    }
    ssrc[w][lane] = srcj;
    #pragma unroll
    for (int h=0;h<8;h++) esc[w][h*68 + lane] = ee[h];
    asm volatile("s_waitcnt lgkmcnt(0)" ::: "memory");
    __builtin_amdgcn_sched_barrier(0);

    for (int j=0; j<cdeg; j+=4){
      int s0 = ssrc[w][j+eo];
      int s1 = ssrc[w][j+2+eo];
      float e0 = esc[w][myh*68 + j+eo];
      float e1 = esc[w][myh*68 + j+2+eo];
      uint2 u0 = *reinterpret_cast<const uint2*>(hb + ((unsigned)s0<<8));
      uint2 u1 = *reinterpret_cast<const uint2*>(hb + ((unsigned)s1<<8));
      acc0 = fmaf(e0, bflo(u0.x), acc0);
      acc1 = fmaf(e0, bfhi(u0.x), acc1);
      acc2 = fmaf(e0, bflo(u0.y), acc2);
      acc3 = fmaf(e0, bfhi(u0.y), acc3);
      acc0 = fmaf(e1, bflo(u1.x), acc0);
      acc1 = fmaf(e1, bfhi(u1.x), acc1);
      acc2 = fmaf(e1, bflo(u1.y), acc2);
      acc3 = fmaf(e1, bfhi(u1.y), acc3);
      dsum += e0 + e1;
    }
  }
  acc0 += __shfl_xor(acc0, 32);
  acc1 += __shfl_xor(acc1, 32);
  acc2 += __shfl_xor(acc2, 32);
  acc3 += __shfl_xor(acc3, 32);
  dsum += __shfl_xor(dsum, 32);

  float inv = 1.f/(dsum + 1e-16f);
  float4 bv = ld4(&bias[c*4]);
  float o0 = fmaf(acc0, inv, bv.x);
  float o1 = fmaf(acc1, inv, bv.y);
  float o2 = fmaf(acc2, inv, bv.z);
  float o3 = fmaf(acc3, inv, bv.w);
  o0 = o0>0.f ? o0 : (__expf(o0)-1.f);
  o1 = o1>0.f ? o1 : (__expf(o1)-1.f);
  o2 = o2>0.f ? o2 : (__expf(o2)-1.f);
  o3 = o3>0.f ? o3 : (__expf(o3)-1.f);
  if (eo == 0){
    unsigned lo = (unsigned)f2bf(o0) | ((unsigned)f2bf(o1)<<16);
    unsigned hi = (unsigned)f2bf(o2) | ((unsigned)f2bf(o3)<<16);
    *reinterpret_cast<uint2*>(&hout[(size_t)n*128 + c*4]) = make_uint2(lo, hi);
  }
}

// =============== fused: layer scores (MFMA) + layer softmax + hfinal@Wout (MFMA) ===============
__global__ __launch_bounds__(256) void k_final2(
    const unsigned short* __restrict__ h0, const unsigned short* __restrict__ h1,
    const unsigned short* __restrict__ h2,
    const unsigned short* __restrict__ WattT, const float* __restrict__ aatt,
    const unsigned short* __restrict__ WoutT,  // [48][128] hi, then [48][128] lo
    const float* __restrict__ bout, float* __restrict__ out, int M)
{
  __shared__ unsigned short hf[128*128];   // hfinal bf16, chunk-XOR-swizzled
  __shared__ float lamS[128][4];
  int t = threadIdx.x, lane = t & 63, w = t >> 6;
  int rA = lane & 15, g = lane >> 4;
  int r0 = blockIdx.x*128 + w*32;
  const unsigned short* hs[3] = {h0, h1, h2};

  // ---- phase 1: per-layer scores via MFMA ----
  float av[8];
  #pragma unroll
  for (int nf=0;nf<8;nf++) av[nf] = aatt[nf*16 + rA];
  int rowc0 = min(r0 + rA,      M-1);
  int rowc1 = min(r0 + 16 + rA, M-1);
  float sc[3][2][4];
  #pragma unroll
  for (int l=0;l<3;l++){
    const unsigned short* A = hs[l];
    f32x4 z = {0.f,0.f,0.f,0.f};
    f32x4 acc[2][8];
    #pragma unroll
    for (int mf=0;mf<2;mf++)
      #pragma unroll
      for (int nf=0;nf<8;nf++) acc[mf][nf] = z;
    #pragma unroll
    for (int ks=0; ks<4; ks++){
      int ko = ks*32 + g*8;
      bf16x8 a0 = *reinterpret_cast<const bf16x8*>(A + (size_t)rowc0*128 + ko);
      bf16x8 a1 = *reinterpret_cast<const bf16x8*>(A + (size_t)rowc1*128 + ko);
      #pragma unroll
      for (int nf=0;nf<8;nf++){
        bf16x8 bf_ = *reinterpret_cast<const bf16x8*>(WattT + (size_t)(nf*16+rA)*128 + ko);
        acc[0][nf] = __builtin_amdgcn_mfma_f32_16x16x32_bf16(a0, bf_, acc[0][nf], 0, 0, 0);
        acc[1][nf] = __builtin_amdgcn_mfma_f32_16x16x32_bf16(a1, bf_, acc[1][nf], 0, 0, 0);
      }
    }
    #pragma unroll
    for (int mf=0;mf<2;mf++){
      #pragma unroll
      for (int r=0;r<4;r++){
        float s = 0.f;
        #pragma unroll
        for (int nf=0;nf<8;nf++) s += ftanh(acc[mf][nf][r]) * av[nf];
        s += __shfl_xor(s, 1);
        s += __shfl_xor(s, 2);
        s += __shfl_xor(s, 4);
        s += __shfl_xor(s, 8);
        sc[l][mf][r] = s;
      }
    }
  }
  // ---- layer softmax -> lam in LDS ----
  if (rA == 0){
    #pragma unroll
    for (int mf=0;mf<2;mf++){
      #pragma unroll
      for (int r=0;r<4;r++){
        float s0 = sc[0][mf][r], s1 = sc[1][mf][r], s2 = sc[2][mf][r];
        float m = fmaxf(s0, fmaxf(s1, s2));
        float e0 = __expf(s0-m), e1 = __expf(s1-m), e2 = __expf(s2-m);
        float inv = 1.f/(e0+e1+e2);
        int rl = w*32 + mf*16 + g*4 + r;
        lamS[rl][0] = e0*inv; lamS[rl][1] = e1*inv; lamS[rl][2] = e2*inv;
      }
    }
  }
  __syncthreads();

  // ---- phase 2: stage hfinal bf16 into LDS (swizzled) ----
  {
    int row = t >> 1, half = t & 1;
    int gr = min(blockIdx.x*128 + row, M-1);
    float l0 = lamS[row][0], l1 = lamS[row][1], l2 = lamS[row][2];
    const uint4* p0 = reinterpret_cast<const uint4*>(h0 + (size_t)gr*128);
    const uint4* p1 = reinterpret_cast<const uint4*>(h1 + (size_t)gr*128);
    const uint4* p2 = reinterpret_cast<const uint4*>(h2 + (size_t)gr*128);
    #pragma unroll
    for (int q=0;q<8;q++){
      int chunk = half*8 + q;
      uint4 u0 = p0[chunk], u1 = p1[chunk], u2 = p2[chunk];
      unsigned ua[4] = {u0.x,u0.y,u0.z,u0.w};
      unsigned ub[4] = {u1.x,u1.y,u1.z,u1.w};
      unsigned uc[4] = {u2.x,u2.y,u2.z,u2.w};
      unsigned short o[8];
      #pragma unroll
      for (int i2=0;i2<4;i2++){
        float f0 = l0*bflo(ua[i2]) + l1*bflo(ub[i2]) + l2*bflo(uc[i2]);
        float f1 = l0*bfhi(ua[i2]) + l1*bfhi(ub[i2]) + l2*bfhi(uc[i2]);
        o[2*i2]   = f2bf(f0);
        o[2*i2+1] = f2bf(f1);
      }
      *reinterpret_cast<uint4*>(&hf[row*128 + ((chunk ^ (row&7))<<3)]) = *reinterpret_cast<const uint4*>(o);
    }
  }
  __syncthreads();

  // ---- phase 3: out = hfinal @ Wout (hi + lo residual) ----
  f32x4 z = {0.f,0.f,0.f,0.f};
  f32x4 oacc[2][3];
  #pragma unroll
  for (int mf=0;mf<2;mf++)
    #pragma unroll
    for (int nf=0;nf<3;nf++) oacc[mf][nf] = z;
  #pragma unroll
  for (int ks=0; ks<4; ks++){
    int cbk = ks*4 + g;
    int ko = ks*32 + g*8;
    bf16x8 a[2];
    #pragma unroll
    for (int mf=0;mf<2;mf++){
      int rl = w*32 + mf*16 + rA;
      a[mf] = *reinterpret_cast<const bf16x8*>(&hf[rl*128 + ((cbk ^ (rl&7))<<3)]);
    }
    #pragma unroll
    for (int nf=0;nf<3;nf++){
      bf16x8 bh = *reinterpret_cast<const bf16x8*>(WoutT + (size_t)(nf*16+rA)*128 + ko);
      bf16x8 bl = *reinterpret_cast<const bf16x8*>(WoutT + 6144 + (size_t)(nf*16+rA)*128 + ko);
      #pragma unroll
      for (int mf=0;mf<2;mf++){
        oacc[mf][nf] = __builtin_amdgcn_mfma_f32_16x16x32_bf16(a[mf], bh, oacc[mf][nf], 0, 0, 0);
        oacc[mf][nf] = __builtin_amdgcn_mfma_f32_16x16x32_bf16(a[mf], bl, oacc[mf][nf], 0, 0, 0);
      }
    }
  }
  float bv[3];
  #pragma unroll
  for (int nf=0;nf<3;nf++){
    int col = nf*16 + rA;
    bv[nf] = (col < 40) ? bout[col] : 0.f;
  }
  #pragma unroll
  for (int mf=0;mf<2;mf++){
    #pragma unroll
    for (int r=0;r<4;r++){
      int grow = r0 + mf*16 + g*4 + r;
      if (grow < M){
        #pragma unroll
        for (int nf=0;nf<3;nf++){
          int col = nf*16 + rA;
          if (col < 40) out[(size_t)grow*40 + col] = oacc[mf][nf][r] + bv[nf];
        }
      }
    }
  }
}

extern "C" void kernel_launch(void* const* d_in, const int* in_sizes, int n_in,
                              void* d_out, int out_size, void* d_ws, size_t ws_size,
                              hipStream_t stream)
{
  const float* x    = (const float*)d_in[0];
  const int*   ei   = (const int*)d_in[1];
  const float* W0   = (const float*)d_in[2];
  const float* as0  = (const float*)d_in[3];
  const float* ad0  = (const float*)d_in[4];
  const float* b0   = (const float*)d_in[5];
  const float* W12  = (const float*)d_in[6];
  const float* as12 = (const float*)d_in[7];
  const float* ad12 = (const float*)d_in[8];
  const float* b12  = (const float*)d_in[9];
  const float* Watt = (const float*)d_in[10];
  const float* aatt = (const float*)d_in[11];
  const float* Wout = (const float*)d_in[12];
  const float* bout = (const float*)d_in[13];
  const int N_ = in_sizes[0] / 128;
  const int E_ = in_sizes[1] / 2;
  const int Et = E_ + N_;
  const int nb = (N_ + 1023) >> 10;

  char* p = (char*)d_ws;
  auto carve = [&](size_t bytes)->char*{ char* r = p; p += (bytes + 255) & ~(size_t)255; return r; };
  unsigned short* xb   = (unsigned short*)carve((size_t)N_*128*2);
  unsigned short* htmp = (unsigned short*)carve((size_t)N_*128*2);
  unsigned short* h0   = (unsigned short*)carve((size_t)N_*128*2);
  unsigned short* h1   = (unsigned short*)carve((size_t)N_*128*2);
  unsigned short* h2   = (unsigned short*)carve((size_t)N_*128*2);
  unsigned short* wsT  = (unsigned short*)carve((size_t)4*18432*2);
  unsigned short* woutT= (unsigned short*)carve((size_t)2*48*128*2);
  float* ssrc_s  = (float*)carve((size_t)N_*8*4);
  float* sdst_s  = (float*)carve((size_t)N_*8*4);
  int* cnt       = (int*)carve((size_t)N_*4);
  int* offv      = (int*)carve((size_t)(N_+1)*4);
  int* blk       = (int*)carve((size_t)64*4);
  int* blkoff    = (int*)carve((size_t)64*4);
  int* bcnt      = (int*)carve((size_t)64*4);
  int* bbase     = (int*)carve((size_t)66*4);
  int* bcursor   = (int*)carve((size_t)64*4);
  uint2* bdata   = (uint2*)carve((size_t)Et*8);
  int* csr       = (int*)carve((size_t)Et*4);

  k_prep<<<4,256,0,stream>>>(W0, W12, Watt, as0, ad0, as12, ad12, wsT);
  k_prep_out<<<1,256,0,stream>>>(Wout, woutT);
  k_xcast<<<(N_*128/8 + 255)/256,256,0,stream>>>(x, xb, N_*128/8);

  hipMemsetAsync(bcnt, 0, 64*4, stream);
  int gB = (Et + 2047)/2048;
  k_bcount<<<gB,256,0,stream>>>(ei, bcnt, E_, Et);
  k_binit<<<1,64,0,stream>>>(bcnt, bbase, bcursor, nb);
  k_bucket<<<gB,256,0,stream>>>(ei, bcursor, bdata, E_, Et);
  k_bhist<<<nb,512,0,stream>>>(bdata, bbase, cnt, N_);
  int nblk = (N_ + 1023)/1024;
  k_scan1<<<nblk,256,0,stream>>>(cnt, blk, N_);
  k_scan2<<<1,64,0,stream>>>(blk, blkoff, offv, N_, nblk);
  k_scan3<<<nblk,256,0,stream>>>(cnt, blkoff, offv, N_);
  k_bscatter<<<nb,512,0,stream>>>(bdata, bbase, offv, csr, N_);

  int gM  = (N_+127)/128;
  int gN4 = (N_+3)/4;
  unsigned short* hl[3] = {h0,h1,h2};
  const unsigned short* hin = xb;
  for (int l=0;l<3;l++){
    const float* bb = (l==0)? b0 : b12 + (size_t)(l-1)*128;
    const unsigned short* Bt = wsT + (size_t)l*18432;
    k_gemm<<<gM,256,0,stream>>>(hin, Bt, htmp, ssrc_s, sdst_s, N_);
    k_aggregate<<<gN4,256,0,stream>>>(offv, csr, htmp, ssrc_s, sdst_s, bb, hl[l], N_);
    hin = hl[l];
  }
  k_final2<<<gM,256,0,stream>>>(h0, h1, h2, wsT + (size_t)3*18432, aatt, woutT, bout, (float*)d_out, N_);
}